// Round 8
// baseline (570.450 us; speedup 1.0000x reference)
//
#include <hip/hip_runtime.h>
#include <hip/hip_bf16.h>

#define B 64
#define N0 2048
#define DEG 16
#define IN_DIM 128
#define H 30
#define NH 11
#define K1 1844
#define K2 1660
#define K3 1494
#define NTOT (B * N0)        /* 131072 */
#define ETOT (NTOT * DEG)    /* 2097152 */
#define EPG (ETOT / B)       /* 32768 edges per graph, contiguous */
#define RSTRIDE 32           /* padded row stride for r, t, h */
#define ESTRIDE1 32768       /* layer-1 CSR capacity per graph */
#define RSEG 16              /* readout segments per graph */

// ---------------------------------------------------------------------------
// Prep: fold layernorm gamma into layer-1 weights; combine rel/root weights.
// ---------------------------------------------------------------------------
__global__ __launch_bounds__(256) void k_prep(
    const float* __restrict__ ln_g, const float* __restrict__ ln_b,
    const float* __restrict__ Wrel1, const float* __restrict__ brel1, const float* __restrict__ Wroot1,
    const float* __restrict__ Wrel2, const float* __restrict__ Wroot2,
    const float* __restrict__ Wrel3, const float* __restrict__ Wroot3,
    float* __restrict__ Wc1, float* __restrict__ S1, float* __restrict__ T1,
    float* __restrict__ Wc2, float* __restrict__ Wc3)
{
    int tid = threadIdx.x;
    for (int i = tid; i < IN_DIM * 60; i += 256) {
        int j = i / 60, c = i - j * 60;
        float w = (c < H) ? Wrel1[j * H + c] : Wroot1[j * H + (c - H)];
        Wc1[i] = w * ln_g[j];
    }
    if (tid < 60) {
        int c = tid;
        float s = 0.f, tt = 0.f;
        for (int j = 0; j < IN_DIM; ++j) {
            float w = (c < H) ? Wrel1[j * H + c] : Wroot1[j * H + (c - H)];
            s += w * ln_g[j];
            tt += w * ln_b[j];
        }
        S1[c] = s;
        T1[c] = (c < H) ? tt : tt + brel1[c - H];
    }
    for (int i = tid; i < H * 60; i += 256) {
        int j = i / 60, c = i - j * 60;
        Wc2[i] = (c < H) ? Wrel2[j * H + c] : Wroot2[j * H + (c - H)];
        Wc3[i] = (c < H) ? Wrel3[j * H + c] : Wroot3[j * H + (c - H)];
    }
}

// ---------------------------------------------------------------------------
// Layer 1 LN+proj, register-blocked: thread = 8 rows x 15 cols. Block = 4
// waves (one 15-col group each, W tile [4][128][16] in LDS), 512 rows.
// ds_read per thread = 512 (vs 1920/row before). x double-buffered.
// ---------------------------------------------------------------------------
__global__ __launch_bounds__(256) void k_lnproj(
    const float* __restrict__ x, const float* __restrict__ Wc,
    const float* __restrict__ S, const float* __restrict__ T,
    float* __restrict__ r, float* __restrict__ t)
{
    __shared__ float wlds[4][IN_DIM][16];
    for (int i = threadIdx.x; i < IN_DIM * 64; i += 256) {
        int k = i >> 6, cc = i & 63;
        int cg = cc >> 4, j = cc & 15;
        wlds[cg][k][j] = (j < 15) ? Wc[k * 60 + cg * 15 + j] : 0.f;
    }
    __syncthreads();
    int lane = threadIdx.x & 63, cg = threadIdx.x >> 6;
    int row0 = blockIdx.x * 512 + lane;
    const float* xb = x + (size_t)row0 * IN_DIM;
    float acc[8][15];
    float sum[8], sumsq[8];
#pragma unroll
    for (int ri = 0; ri < 8; ++ri) {
        sum[ri] = 0.f; sumsq[ri] = 0.f;
#pragma unroll
        for (int c = 0; c < 15; ++c) acc[ri][c] = 0.f;
    }
    float4 cur[8], nxt[8];
#pragma unroll
    for (int ri = 0; ri < 8; ++ri)
        cur[ri] = *(const float4*)(xb + (size_t)ri * 64 * IN_DIM);
    for (int kb = 0; kb < 32; ++kb) {
        if (kb < 31) {
#pragma unroll
            for (int ri = 0; ri < 8; ++ri)
                nxt[ri] = *(const float4*)(xb + (size_t)ri * 64 * IN_DIM + (kb + 1) * 4);
        }
#pragma unroll
        for (int kk = 0; kk < 4; ++kk) {
            int k = kb * 4 + kk;
            float4 w0 = *(const float4*)&wlds[cg][k][0];
            float4 w1 = *(const float4*)&wlds[cg][k][4];
            float4 w2 = *(const float4*)&wlds[cg][k][8];
            float4 w3 = *(const float4*)&wlds[cg][k][12];   // .w is pad
#pragma unroll
            for (int ri = 0; ri < 8; ++ri) {
                float xv = (kk == 0) ? cur[ri].x : (kk == 1) ? cur[ri].y
                          : (kk == 2) ? cur[ri].z : cur[ri].w;
                sum[ri] += xv; sumsq[ri] += xv * xv;
                acc[ri][0]  += xv * w0.x; acc[ri][1]  += xv * w0.y;
                acc[ri][2]  += xv * w0.z; acc[ri][3]  += xv * w0.w;
                acc[ri][4]  += xv * w1.x; acc[ri][5]  += xv * w1.y;
                acc[ri][6]  += xv * w1.z; acc[ri][7]  += xv * w1.w;
                acc[ri][8]  += xv * w2.x; acc[ri][9]  += xv * w2.y;
                acc[ri][10] += xv * w2.z; acc[ri][11] += xv * w2.w;
                acc[ri][12] += xv * w3.x; acc[ri][13] += xv * w3.y;
                acc[ri][14] += xv * w3.z;
            }
        }
        if (kb < 31) {
#pragma unroll
            for (int ri = 0; ri < 8; ++ri) cur[ri] = nxt[ri];
        }
    }
    bool isR = (cg < 2);
    int cbase = (cg & 1) * 15;
    float* outp = isR ? r : t;
    float sS[15], sT[15];
#pragma unroll
    for (int c = 0; c < 15; ++c) { sS[c] = S[cg * 15 + c]; sT[c] = T[cg * 15 + c]; }
#pragma unroll
    for (int ri = 0; ri < 8; ++ri) {
        int row = row0 + ri * 64;
        float mean = sum[ri] * (1.f / 128.f);
        float var = sumsq[ri] * (1.f / 128.f) - mean * mean;
        float rstd = 1.0f / sqrtf(var + 1e-5f);
        float* op = outp + (size_t)row * RSTRIDE + cbase;
#pragma unroll
        for (int c = 0; c < 15; ++c)
            op[c] = rstd * (acc[ri][c] - mean * sS[c]) + sT[c];
        if (cg & 1) {
            outp[(size_t)row * RSTRIDE + 30] = 0.f;
            outp[(size_t)row * RSTRIDE + 31] = 0.f;
        }
    }
}

// ---------------------------------------------------------------------------
// Pooled projection v2 (layers 2/3), register-blocked: thread = 4 rows x 15
// cols; W tile [4][32][16] in LDS. r = val*(h@Wrel); t = val*(h@Wroot)+brel.
// ---------------------------------------------------------------------------
__global__ __launch_bounds__(256) void k_proj30p(
    const float* __restrict__ hbuf, const int* __restrict__ sidx,
    const float* __restrict__ score, const float* __restrict__ Wc,
    const float* __restrict__ brel, float* __restrict__ r, float* __restrict__ t,
    int n_old, int k)
{
    __shared__ float wlds[4][32][16];
    for (int i = threadIdx.x; i < 30 * 64; i += 256) {
        int m = i >> 6, cc = i & 63;
        int cg = cc >> 4, j = cc & 15;
        wlds[cg][m][j] = (j < 15) ? Wc[m * 60 + cg * 15 + j] : 0.f;
    }
    __syncthreads();
    int lane = threadIdx.x & 63, cg = threadIdx.x >> 6;
    int row0 = blockIdx.x * 256 + lane;
    float acc[4][15];
#pragma unroll
    for (int ri = 0; ri < 4; ++ri)
#pragma unroll
        for (int c = 0; c < 15; ++c) acc[ri][c] = 0.f;
    float vals[4];
    const float* hp[4];
#pragma unroll
    for (int ri = 0; ri < 4; ++ri) {
        int row = row0 + ri * 64;
        int g = row / k, j = row - g * k;
        int idx = sidx[g * k + j];
        vals[ri] = score[g * n_old + idx];
        hp[ri] = hbuf + (size_t)(g * n_old + idx) * RSTRIDE;
    }
    for (int mb = 0; mb < 7; ++mb) {
        float4 cur[4];
#pragma unroll
        for (int ri = 0; ri < 4; ++ri) cur[ri] = *(const float4*)(hp[ri] + mb * 4);
#pragma unroll
        for (int kk = 0; kk < 4; ++kk) {
            int m = mb * 4 + kk;
            float4 w0 = *(const float4*)&wlds[cg][m][0];
            float4 w1 = *(const float4*)&wlds[cg][m][4];
            float4 w2 = *(const float4*)&wlds[cg][m][8];
            float4 w3 = *(const float4*)&wlds[cg][m][12];
#pragma unroll
            for (int ri = 0; ri < 4; ++ri) {
                float xv = (kk == 0) ? cur[ri].x : (kk == 1) ? cur[ri].y
                          : (kk == 2) ? cur[ri].z : cur[ri].w;
                acc[ri][0]  += xv * w0.x; acc[ri][1]  += xv * w0.y;
                acc[ri][2]  += xv * w0.z; acc[ri][3]  += xv * w0.w;
                acc[ri][4]  += xv * w1.x; acc[ri][5]  += xv * w1.y;
                acc[ri][6]  += xv * w1.z; acc[ri][7]  += xv * w1.w;
                acc[ri][8]  += xv * w2.x; acc[ri][9]  += xv * w2.y;
                acc[ri][10] += xv * w2.z; acc[ri][11] += xv * w2.w;
                acc[ri][12] += xv * w3.x; acc[ri][13] += xv * w3.y;
                acc[ri][14] += xv * w3.z;
            }
        }
    }
    {   // tail m = 28, 29
        float2 h2[4];
#pragma unroll
        for (int ri = 0; ri < 4; ++ri) h2[ri] = *(const float2*)(hp[ri] + 28);
#pragma unroll
        for (int kk = 0; kk < 2; ++kk) {
            int m = 28 + kk;
            float4 w0 = *(const float4*)&wlds[cg][m][0];
            float4 w1 = *(const float4*)&wlds[cg][m][4];
            float4 w2 = *(const float4*)&wlds[cg][m][8];
            float4 w3 = *(const float4*)&wlds[cg][m][12];
#pragma unroll
            for (int ri = 0; ri < 4; ++ri) {
                float xv = (kk == 0) ? h2[ri].x : h2[ri].y;
                acc[ri][0]  += xv * w0.x; acc[ri][1]  += xv * w0.y;
                acc[ri][2]  += xv * w0.z; acc[ri][3]  += xv * w0.w;
                acc[ri][4]  += xv * w1.x; acc[ri][5]  += xv * w1.y;
                acc[ri][6]  += xv * w1.z; acc[ri][7]  += xv * w1.w;
                acc[ri][8]  += xv * w2.x; acc[ri][9]  += xv * w2.y;
                acc[ri][10] += xv * w2.z; acc[ri][11] += xv * w2.w;
                acc[ri][12] += xv * w3.x; acc[ri][13] += xv * w3.y;
                acc[ri][14] += xv * w3.z;
            }
        }
    }
    bool isR = (cg < 2);
    int cbase = (cg & 1) * 15;
    float* outp = isR ? r : t;
    float sB[15];
#pragma unroll
    for (int c = 0; c < 15; ++c) sB[c] = isR ? 0.f : brel[cbase + c];
#pragma unroll
    for (int ri = 0; ri < 4; ++ri) {
        int row = row0 + ri * 64;
        float val = vals[ri];
        float* op = outp + (size_t)row * RSTRIDE + cbase;
#pragma unroll
        for (int c = 0; c < 15; ++c)
            op[c] = val * acc[ri][c] + sB[c];
        if (cg & 1) {
            outp[(size_t)row * RSTRIDE + 30] = 0.f;
            outp[(size_t)row * RSTRIDE + 31] = 0.f;
        }
    }
}

// ---------------------------------------------------------------------------
// Layer-1 counting sort (only sort in the pipeline now).
// ---------------------------------------------------------------------------
__global__ __launch_bounds__(1024) void k_hist1(
    const int* __restrict__ dst, unsigned short* __restrict__ rank,
    int* __restrict__ chunkCnt)
{
    __shared__ unsigned int cnt[2048];
    int chunk = blockIdx.x, g = chunk >> 2;
    for (int i = threadIdx.x; i < 2048; i += 1024) cnt[i] = 0;
    __syncthreads();
    int e0 = chunk * 8192;
#pragma unroll
    for (int u = 0; u < 8; ++u) {
        int e = e0 + u * 1024 + threadIdx.x;
        int d = dst[e] - g * N0;
        rank[e] = (unsigned short)atomicAdd(&cnt[d], 1u);
    }
    __syncthreads();
    for (int i = threadIdx.x; i < 2048; i += 1024) chunkCnt[chunk * 2048 + i] = cnt[i];
}

__global__ __launch_bounds__(1024) void k_scan(
    int* __restrict__ chunkCnt, int* __restrict__ runStart, int* __restrict__ runLen)
{
    __shared__ int bufA[2048], bufB[2048];
    int g = blockIdx.x;
    int c0[2], c1[2], c2[2], tt[2];
    for (int h2 = 0; h2 < 2; ++h2) {
        int d = threadIdx.x + h2 * 1024;
        c0[h2] = chunkCnt[(g * 4 + 0) * 2048 + d];
        c1[h2] = chunkCnt[(g * 4 + 1) * 2048 + d];
        c2[h2] = chunkCnt[(g * 4 + 2) * 2048 + d];
        int c3 = chunkCnt[(g * 4 + 3) * 2048 + d];
        tt[h2] = c0[h2] + c1[h2] + c2[h2] + c3;
        bufA[d] = tt[h2];
    }
    __syncthreads();
    int* s_ = bufA; int* d_ = bufB;
    for (int off = 1; off < 2048; off <<= 1) {
        for (int h2 = 0; h2 < 2; ++h2) {
            int d = threadIdx.x + h2 * 1024;
            int v = s_[d];
            if (d >= off) v += s_[d - off];
            d_[d] = v;
        }
        __syncthreads();
        int* tmp = s_; s_ = d_; d_ = tmp;
    }
    for (int h2 = 0; h2 < 2; ++h2) {
        int d = threadIdx.x + h2 * 1024;
        int ex = s_[d] - tt[h2];
        runStart[g * 2048 + d] = ex;
        runLen[g * 2048 + d] = tt[h2];
        chunkCnt[(g * 4 + 0) * 2048 + d] = ex;
        chunkCnt[(g * 4 + 1) * 2048 + d] = ex + c0[h2];
        chunkCnt[(g * 4 + 2) * 2048 + d] = ex + c0[h2] + c1[h2];
        chunkCnt[(g * 4 + 3) * 2048 + d] = ex + c0[h2] + c1[h2] + c2[h2];
    }
}

__global__ __launch_bounds__(1024) void k_scat1(
    const int* __restrict__ src, const int* __restrict__ dst, const float* __restrict__ ew,
    const unsigned short* __restrict__ rank, const int* __restrict__ chunkOff,
    float2* __restrict__ sOut)
{
    int chunk = blockIdx.x, g = chunk >> 2;
    int e0 = chunk * 8192;
#pragma unroll
    for (int u = 0; u < 8; ++u) {
        int e = e0 + u * 1024 + threadIdx.x;
        int d = dst[e] - g * N0;
        int pos = chunkOff[chunk * 2048 + d] + (int)rank[e];
        sOut[(size_t)g * ESTRIDE1 + pos] = make_float2(__int_as_float(src[e]), ew[e]);
    }
}

// ---------------------------------------------------------------------------
// Run-major aggregation over the LAYER-1 CSR for ALL layers. LVL = pooling
// depth: node -> ancestor v1 via sidx chain; per-edge liveness/renumbering
// via mapc (w -> 0 for dropped srcs). Zero atomics; fused +t/relu and score.
// ---------------------------------------------------------------------------
template<int LVL>
__global__ __launch_bounds__(256) void k_gather(
    const float2* __restrict__ sE, const int* __restrict__ runS, const int* __restrict__ runL,
    const int* __restrict__ ind1, const int* __restrict__ ind2, const int* __restrict__ mapc,
    const float* __restrict__ rp, const float* __restrict__ t, float* __restrict__ h,
    const float* __restrict__ poolw, float* __restrict__ score,
    int n, int rK, int nblocks)
{
    int b = blockIdx.x;
    int cpx = nblocks >> 3;                 // XCD-chunked swizzle
    b = (b & 7) * cpx + (b >> 3);
    int slot = threadIdx.x >> 5, j = threadIdx.x & 31;
    int v = b * 8 + slot;
    int g = v / n;
    int local = v - g * n;
    int v1 = local;
    if (LVL >= 2) v1 = ind2[g * K2 + v1];
    if (LVL >= 1) v1 = ind1[g * K1 + v1];
    int s0 = runS[g * 2048 + v1], len = runL[g * 2048 + v1];
    const float2* meta = sE + (size_t)g * ESTRIDE1 + s0;
    int rbase = g * rK;
    float acc = 0.f;
    for (int c = 0; c < len; c += 8) {
        int lim = len - c; if (lim > 8) lim = 8;
        float2 m[8];
#pragma unroll
        for (int u = 0; u < 8; ++u) m[u] = meta[c + (u < lim ? u : 0)];
        int rowv[8]; float wv[8];
#pragma unroll
        for (int u = 0; u < 8; ++u) {
            int srcg = __float_as_int(m[u].x);
            float w = (u < lim) ? m[u].y : 0.f;
            if (LVL == 0) {
                rowv[u] = srcg;
            } else {
                int ss = mapc[srcg];
                rowv[u] = rbase + (ss < 0 ? 0 : ss);
                w = (ss < 0) ? 0.f : w;
            }
            wv[u] = w;
        }
#pragma unroll
        for (int u = 0; u < 8; ++u)
            acc += rp[(size_t)rowv[u] * RSTRIDE + j] * wv[u];
    }
    float wj = (j < H) ? poolw[j] : 0.f;
    float hval = 0.f;
    if (j < H) {
        hval = fmaxf(acc + t[(size_t)v * RSTRIDE + j], 0.f);
        h[(size_t)v * RSTRIDE + j] = hval;
    }
    float p = hval * wj, q = wj * wj;
#pragma unroll
    for (int off = 16; off > 0; off >>= 1) {
        p += __shfl_xor(p, off, 32);
        q += __shfl_xor(q, off, 32);
    }
    if (j == 0) score[v] = tanhf(p / sqrtf(q));
}

// ---------------------------------------------------------------------------
// Top-k (desc score, asc idx; jax.lax.top_k tie-break) + cumulative map.
// ---------------------------------------------------------------------------
__global__ __launch_bounds__(1024) void k_topk_map(
    const float* __restrict__ score, int* __restrict__ sidx, int* __restrict__ mapc,
    int n, int k, int first)
{
    __shared__ unsigned long long keys[2048];
    __shared__ int inv[2048];
    int g = blockIdx.x;
    for (int i = threadIdx.x; i < 2048; i += 1024) {
        unsigned long long key = ~0ull;
        if (i < n) {
            float s = score[g * n + i];
            if (s == 0.f) s = 0.f;                 // canonicalize -0 -> +0
            unsigned u = __float_as_uint(s);
            unsigned asc = (u & 0x80000000u) ? ~u : (u | 0x80000000u);
            unsigned desc = ~asc;
            key = ((unsigned long long)desc << 32) | (unsigned)i;
        }
        keys[i] = key;
        inv[i] = -1;
    }
    __syncthreads();
    for (int kk = 2; kk <= 2048; kk <<= 1) {
        for (int jj = kk >> 1; jj > 0; jj >>= 1) {
            for (int i = threadIdx.x; i < 2048; i += 1024) {
                int ixj = i ^ jj;
                if (ixj > i) {
                    unsigned long long a = keys[i], bb = keys[ixj];
                    bool up = ((i & kk) == 0);
                    if ((a > bb) == up) { keys[i] = bb; keys[ixj] = a; }
                }
            }
            __syncthreads();
        }
    }
    for (int j = threadIdx.x; j < k; j += 1024) {
        int idx = (int)(keys[j] & 0xffffffffu);
        sidx[g * k + j] = idx;
        inv[idx] = j;
    }
    __syncthreads();
    if (first) {
        for (int v = threadIdx.x; v < N0; v += 1024)
            mapc[g * N0 + v] = inv[v];
    } else {
        for (int v = threadIdx.x; v < N0; v += 1024) {
            int m = mapc[g * N0 + v];
            mapc[g * N0 + v] = (m >= 0) ? inv[m] : -1;
        }
    }
}

// ---------------------------------------------------------------------------
// Segmented readout: grid (RSEG, B). Partial [max;sum] over a row slice.
// ---------------------------------------------------------------------------
__global__ __launch_bounds__(256) void k_rpart(
    const float* __restrict__ hbuf, const int* __restrict__ sidx,
    const float* __restrict__ score, float* __restrict__ pmax, float* __restrict__ psum,
    int n_old, int k)
{
    __shared__ float smax[8][32], ssum[8][32];
    int g = blockIdx.y, seg = blockIdx.x;
    int clen = (k + RSEG - 1) / RSEG;
    int start = seg * clen;
    int end = start + clen; if (end > k) end = k;
    int f = threadIdx.x & 31, rr = threadIdx.x >> 5;
    float mx = -INFINITY, sm = 0.f;
    if (f < H) {
        for (int j = start + rr; j < end; j += 8) {
            int idx = sidx[g * k + j];
            float val = score[g * n_old + idx];
            float v = hbuf[(size_t)(g * n_old + idx) * RSTRIDE + f] * val;
            mx = fmaxf(mx, v);
            sm += v;
        }
    }
    smax[rr][f] = mx; ssum[rr][f] = sm;
    __syncthreads();
    if (rr == 0) {
        for (int q = 1; q < 8; ++q) { mx = fmaxf(mx, smax[q][f]); sm += ssum[q][f]; }
        pmax[(g * RSEG + seg) * 32 + f] = mx;
        psum[(g * RSEG + seg) * 32 + f] = sm;
    }
}

// Finalize all 3 readouts + z = relu(x1+x2+x3). grid B, block 64.
__global__ __launch_bounds__(64) void k_zfin(
    const float* __restrict__ pm1, const float* __restrict__ ps1,
    const float* __restrict__ pm2, const float* __restrict__ ps2,
    const float* __restrict__ pm3, const float* __restrict__ ps3,
    float* __restrict__ z)
{
    int g = blockIdx.x, c = threadIdx.x;
    if (c >= 60) return;
    float v1, v2, v3;
    if (c < H) {
        float m1 = -INFINITY, m2 = -INFINITY, m3 = -INFINITY;
        for (int s = 0; s < RSEG; ++s) {
            m1 = fmaxf(m1, pm1[(g * RSEG + s) * 32 + c]);
            m2 = fmaxf(m2, pm2[(g * RSEG + s) * 32 + c]);
            m3 = fmaxf(m3, pm3[(g * RSEG + s) * 32 + c]);
        }
        v1 = m1; v2 = m2; v3 = m3;
    } else {
        int f = c - H;
        float s1 = 0.f, s2 = 0.f, s3 = 0.f;
        for (int s = 0; s < RSEG; ++s) {
            s1 += ps1[(g * RSEG + s) * 32 + f];
            s2 += ps2[(g * RSEG + s) * 32 + f];
            s3 += ps3[(g * RSEG + s) * 32 + f];
        }
        v1 = s1 / (float)K1; v2 = s2 / (float)K2; v3 = s3 / (float)K3;
    }
    z[g * 60 + c] = fmaxf(v1 + v2 + v3, 0.f);
}

// a1[h,b,o] = relu(sum_d z[b,d]*W1[h,d,o] + b1[h,o]),  o<240, d<60
__global__ __launch_bounds__(256) void k_mlp1(
    const float* __restrict__ z, const float* __restrict__ W,
    const float* __restrict__ bias, float* __restrict__ a)
{
    int hb = blockIdx.x, hh = hb >> 6, b = hb & 63;
    __shared__ float zr[60];
    if (threadIdx.x < 60) zr[threadIdx.x] = z[b * 60 + threadIdx.x];
    __syncthreads();
    int o = threadIdx.x;
    if (o < 240) {
        float acc = bias[hh * 240 + o];
        const float* Wp = W + hh * 60 * 240;
#pragma unroll
        for (int d = 0; d < 60; ++d) acc += zr[d] * Wp[d * 240 + o];
        a[(hh * B + b) * 240 + o] = fmaxf(acc, 0.f);
    }
}

// a2 GEMM: grid (11 heads x 15 col-tiles of 64); a1 tile in LDS.
__global__ __launch_bounds__(256) void k_mlp2(
    const float* __restrict__ a1, const float* __restrict__ W,
    const float* __restrict__ bias, float* __restrict__ a2)
{
    __shared__ float a1t[64 * 240];
    int hh = blockIdx.x / 15, ct = blockIdx.x % 15;
    const float4* ag = (const float4*)(a1 + (size_t)hh * B * 240);
    for (int i = threadIdx.x; i < 64 * 240 / 4; i += 256)
        ((float4*)a1t)[i] = ag[i];
    __syncthreads();
    int col = threadIdx.x & 63, rg = threadIdx.x >> 6;
    const float* Wp = W + (size_t)hh * 240 * 960 + ct * 64 + col;
    float acc[16];
#pragma unroll
    for (int i = 0; i < 16; ++i) acc[i] = 0.f;
#pragma unroll 4
    for (int o = 0; o < 240; ++o) {
        float w = Wp[(size_t)o * 960];
        const float* ar = &a1t[0];
#pragma unroll
        for (int i = 0; i < 16; ++i)
            acc[i] += w * ar[(rg * 16 + i) * 240 + o];
    }
    float bv = bias[hh * 960 + ct * 64 + col];
#pragma unroll
    for (int i = 0; i < 16; ++i)
        a2[((size_t)hh * B + rg * 16 + i) * 960 + ct * 64 + col] =
            fmaxf(acc[i] + bv, 0.f);
}

// out[h,b,q] = sum_p a2[h,b,p]*W3[h,p,q] + b3[h,q],  q<8, p<960
__global__ __launch_bounds__(64) void k_mlp3(
    const float* __restrict__ a2, const float* __restrict__ W,
    const float* __restrict__ bias, float* __restrict__ out)
{
    int hb = blockIdx.x, hh = hb >> 6, b = hb & 63;
    __shared__ float ar[960];
    __shared__ float part[64];
    for (int i = threadIdx.x; i < 960; i += 64) ar[i] = a2[(hh * B + b) * 960 + i];
    __syncthreads();
    int q = threadIdx.x & 7, c = threadIdx.x >> 3;
    const float* Wp = W + hh * 960 * 8;
    float acc = 0.f;
    for (int p = c; p < 960; p += 8) acc += ar[p] * Wp[p * 8 + q];
    part[threadIdx.x] = acc;
    __syncthreads();
    if (threadIdx.x < 8) {
        float s = bias[hh * 8 + threadIdx.x];
        for (int cc = 0; cc < 8; ++cc) s += part[cc * 8 + threadIdx.x];
        out[(hh * B + b) * 8 + threadIdx.x] = s;
    }
}

// ---------------------------------------------------------------------------
extern "C" void kernel_launch(void* const* d_in, const int* in_sizes, int n_in,
                              void* d_out, int out_size, void* d_ws, size_t ws_size,
                              hipStream_t stream)
{
    const float* x       = (const float*)d_in[0];
    const int*   eidx    = (const int*)d_in[1];
    const int*   src0    = eidx;
    const int*   dst0    = eidx + ETOT;
    const float* ew0     = (const float*)d_in[2];
    const float* ln_g    = (const float*)d_in[4];
    const float* ln_b    = (const float*)d_in[5];
    const float* W_rel1  = (const float*)d_in[6];
    const float* b_rel1  = (const float*)d_in[7];
    const float* W_root1 = (const float*)d_in[8];
    const float* W_rel2  = (const float*)d_in[9];
    const float* b_rel2  = (const float*)d_in[10];
    const float* W_root2 = (const float*)d_in[11];
    const float* W_rel3  = (const float*)d_in[12];
    const float* b_rel3  = (const float*)d_in[13];
    const float* W_root3 = (const float*)d_in[14];
    const float* pool_w1 = (const float*)d_in[15];
    const float* pool_w2 = (const float*)d_in[16];
    const float* pool_w3 = (const float*)d_in[17];
    const float* head_W1 = (const float*)d_in[18];
    const float* head_b1 = (const float*)d_in[19];
    const float* head_W2 = (const float*)d_in[20];
    const float* head_b2 = (const float*)d_in[21];
    const float* head_W3 = (const float*)d_in[22];
    const float* head_b3 = (const float*)d_in[23];

    // ---- workspace carve (~75 MB) ----
    float* ws     = (float*)d_ws;
    float* rbuf   = ws;                               // NTOT*32
    float* tbuf   = rbuf + (size_t)NTOT * RSTRIDE;    // NTOT*32
    float* abuf   = tbuf + (size_t)NTOT * RSTRIDE;    // NTOT*32 (h)
    float2* sA    = (float2*)(abuf + (size_t)NTOT * RSTRIDE); // B*ESTRIDE1
    float* score  = (float*)(sA + (size_t)B * ESTRIDE1);      // NTOT
    int*   sidxA  = (int*)(score + NTOT);             // B*K1
    int*   sidxB  = sidxA + B * K1;                   // B*K2
    int*   sidxC  = sidxB + B * K2;                   // B*K3
    int*   mapc   = sidxC + B * K3;                   // NTOT
    int*   runSA  = mapc + NTOT;                      // B*2048
    int*   runLA  = runSA + B * 2048;                 // B*2048
    float* pm1    = (float*)(runLA + B * 2048);       // B*RSEG*32 each
    float* ps1    = pm1 + B * RSEG * 32;
    float* pm2    = ps1 + B * RSEG * 32;
    float* ps2    = pm2 + B * RSEG * 32;
    float* pm3    = ps2 + B * RSEG * 32;
    float* ps3    = pm3 + B * RSEG * 32;
    float* zb     = ps3 + B * RSEG * 32;              // B*60
    float* Wc1    = zb + B * 60;                      // 128*60
    float* S1     = Wc1 + IN_DIM * 60;
    float* T1     = S1 + 60;
    float* Wc2    = T1 + 60;                          // 30*60
    float* Wc3    = Wc2 + H * 60;
    // aliases into abuf (dead before gather1): chunk counters + per-edge ranks
    int* chunkBuf         = (int*)abuf;                                  // 256*2048 ints
    unsigned short* rank  = (unsigned short*)((char*)abuf + (4u << 20)); // ETOT u16
    // heads alias rbuf (dead after layer-3 gather)
    float* a1 = rbuf;
    float* a2 = a1 + NH * B * 240;

    k_prep<<<1, 256, 0, stream>>>(ln_g, ln_b, W_rel1, b_rel1, W_root1,
                                  W_rel2, W_root2, W_rel3, W_root3,
                                  Wc1, S1, T1, Wc2, Wc3);

    // ---- layer-1 CSR (the only sort) ----
    k_hist1<<<256, 1024, 0, stream>>>(dst0, rank, chunkBuf);
    k_scan<<<B, 1024, 0, stream>>>(chunkBuf, runSA, runLA);
    k_scat1<<<256, 1024, 0, stream>>>(src0, dst0, ew0, rank, chunkBuf, sA);

    // ---- layer 1 ----
    k_lnproj<<<NTOT / 512, 256, 0, stream>>>(x, Wc1, S1, T1, rbuf, tbuf);
    k_gather<0><<<NTOT / 8, 256, 0, stream>>>(sA, runSA, runLA, nullptr, nullptr, nullptr,
                                              rbuf, tbuf, abuf, pool_w1, score,
                                              N0, N0, NTOT / 8);
    k_topk_map<<<B, 1024, 0, stream>>>(score, sidxA, mapc, N0, K1, 1);
    k_rpart<<<dim3(RSEG, B), 256, 0, stream>>>(abuf, sidxA, score, pm1, ps1, N0, K1);
    k_proj30p<<<B * K1 / 256, 256, 0, stream>>>(abuf, sidxA, score, Wc2, b_rel2,
                                                rbuf, tbuf, N0, K1);

    // ---- layer 2 (no sort: reuse layer-1 runs via sidxA + mapc filter) ----
    k_gather<1><<<B * K1 / 8, 256, 0, stream>>>(sA, runSA, runLA, sidxA, nullptr, mapc,
                                                rbuf, tbuf, abuf, pool_w2, score,
                                                K1, K1, B * K1 / 8);
    k_topk_map<<<B, 1024, 0, stream>>>(score, sidxB, mapc, K1, K2, 0);
    k_rpart<<<dim3(RSEG, B), 256, 0, stream>>>(abuf, sidxB, score, pm2, ps2, K1, K2);
    k_proj30p<<<B * K2 / 256, 256, 0, stream>>>(abuf, sidxB, score, Wc3, b_rel3,
                                                rbuf, tbuf, K1, K2);

    // ---- layer 3 ----
    k_gather<2><<<B * K2 / 8, 256, 0, stream>>>(sA, runSA, runLA, sidxA, sidxB, mapc,
                                                rbuf, tbuf, abuf, pool_w3, score,
                                                K2, K2, B * K2 / 8);
    k_topk_map<<<B, 1024, 0, stream>>>(score, sidxC, mapc, K2, K3, 0);
    k_rpart<<<dim3(RSEG, B), 256, 0, stream>>>(abuf, sidxC, score, pm3, ps3, K2, K3);

    // ---- heads ----
    k_zfin<<<B, 64, 0, stream>>>(pm1, ps1, pm2, ps2, pm3, ps3, zb);
    k_mlp1<<<NH * B, 256, 0, stream>>>(zb, head_W1, head_b1, a1);
    k_mlp2<<<NH * 15, 256, 0, stream>>>(a1, head_W2, head_b2, a2);
    k_mlp3<<<NH * B, 64, 0, stream>>>(a2, head_W3, head_b3, (float*)d_out);
}

// Round 9
// 567.986 us; speedup vs baseline: 1.0043x; 1.0043x over previous
//
#include <hip/hip_runtime.h>
#include <hip/hip_bf16.h>

#define B 64
#define N0 2048
#define DEG 16
#define IN_DIM 128
#define H 30
#define NH 11
#define K1 1844
#define K2 1660
#define K3 1494
#define NTOT (B * N0)        /* 131072 */
#define ETOT (NTOT * DEG)    /* 2097152 */
#define RSTRIDE 32           /* row stride for h */
#define RT 64                /* fused r|t row stride: r cols 0-31, t cols 32-63 */
#define ESTRIDE1 32768       /* layer-1 CSR capacity per graph */
#define RSEG 16              /* readout segments per graph */

// ---------------------------------------------------------------------------
// Prep: fold layernorm gamma into layer-1 weights; combine rel/root weights.
// ---------------------------------------------------------------------------
__global__ __launch_bounds__(256) void k_prep(
    const float* __restrict__ ln_g, const float* __restrict__ ln_b,
    const float* __restrict__ Wrel1, const float* __restrict__ brel1, const float* __restrict__ Wroot1,
    const float* __restrict__ Wrel2, const float* __restrict__ Wroot2,
    const float* __restrict__ Wrel3, const float* __restrict__ Wroot3,
    float* __restrict__ Wc1, float* __restrict__ S1, float* __restrict__ T1,
    float* __restrict__ Wc2, float* __restrict__ Wc3)
{
    int tid = threadIdx.x;
    for (int i = tid; i < IN_DIM * 60; i += 256) {
        int j = i / 60, c = i - j * 60;
        float w = (c < H) ? Wrel1[j * H + c] : Wroot1[j * H + (c - H)];
        Wc1[i] = w * ln_g[j];
    }
    if (tid < 60) {
        int c = tid;
        float s = 0.f, tt = 0.f;
        for (int j = 0; j < IN_DIM; ++j) {
            float w = (c < H) ? Wrel1[j * H + c] : Wroot1[j * H + (c - H)];
            s += w * ln_g[j];
            tt += w * ln_b[j];
        }
        S1[c] = s;
        T1[c] = (c < H) ? tt : tt + brel1[c - H];
    }
    for (int i = tid; i < H * 60; i += 256) {
        int j = i / 60, c = i - j * 60;
        Wc2[i] = (c < H) ? Wrel2[j * H + c] : Wroot2[j * H + (c - H)];
        Wc3[i] = (c < H) ? Wrel3[j * H + c] : Wroot3[j * H + (c - H)];
    }
}

// ---------------------------------------------------------------------------
// Layer 1 LN+proj v6: WAVE-PER-ROW, W columns in VGPRs.
// Lane c holds Wc1[:,c] (128 VGPR, loaded once from LDS). Per row: x is
// wave-uniform -> scalar/broadcast loads (1 transaction); LN sums via
// per-lane coalesced loads + 64-lane shfl butterfly; 128 FMA with 2-way
// split accumulator (covers 4-cyc dep latency at 2 waves/SIMD); one
// coalesced 60-lane store to rt[row][64] (r: cols 0-29, t: cols 32-61).
// ---------------------------------------------------------------------------
__global__ __launch_bounds__(256) void k_lnproj(
    const float* __restrict__ x, const float* __restrict__ Wc,
    const float* __restrict__ S, const float* __restrict__ T,
    float* __restrict__ rt)
{
    __shared__ float wlds[IN_DIM * 60];
    for (int i = threadIdx.x; i < IN_DIM * 60 / 4; i += 256)
        ((float4*)wlds)[i] = ((const float4*)Wc)[i];
    __syncthreads();
    int lane = threadIdx.x & 63;
    int wid = __builtin_amdgcn_readfirstlane(threadIdx.x >> 6);
    int c = (lane < 60) ? lane : 59;            // clamp idle lanes (no OOB)
    float wreg[IN_DIM];
#pragma unroll
    for (int k = 0; k < IN_DIM; ++k) wreg[k] = wlds[k * 60 + c];
    float Sc = S[c], Tc = T[c];
    int outc = (c < 30) ? c : c + 2;            // r cols 0-29, t cols 32-61
    int rowbase = (blockIdx.x * 4 + wid) * 64;  // uniform (readfirstlane'd wid)
    for (int rr = 0; rr < 64; ++rr) {
        int row = rowbase + rr;                 // uniform
        const float4* xr4 = (const float4*)(x + (size_t)row * IN_DIM);
        // lane-parallel LN partial sums (coalesced 256B loads)
        float xa = x[(size_t)row * IN_DIM + lane];
        float xb = x[(size_t)row * IN_DIM + 64 + lane];
        float s1 = xa + xb;
        float s2 = xa * xa + xb * xb;
#pragma unroll
        for (int off = 32; off > 0; off >>= 1) {
            s1 += __shfl_xor(s1, off, 64);
            s2 += __shfl_xor(s2, off, 64);
        }
        float mean = s1 * (1.f / 128.f);
        float var = s2 * (1.f / 128.f) - mean * mean;
        float rstd = 1.0f / sqrtf(var + 1e-5f);
        float acc0 = 0.f, acc1 = 0.f;           // 2 chains: hide FMA latency
#pragma unroll
        for (int q = 0; q < 32; q += 2) {
            float4 xq0 = xr4[q];                // uniform addr: s_load/broadcast
            float4 xq1 = xr4[q + 1];
            acc0 = fmaf(xq0.x, wreg[q * 4 + 0], acc0);
            acc1 = fmaf(xq1.x, wreg[q * 4 + 4], acc1);
            acc0 = fmaf(xq0.y, wreg[q * 4 + 1], acc0);
            acc1 = fmaf(xq1.y, wreg[q * 4 + 5], acc1);
            acc0 = fmaf(xq0.z, wreg[q * 4 + 2], acc0);
            acc1 = fmaf(xq1.z, wreg[q * 4 + 6], acc1);
            acc0 = fmaf(xq0.w, wreg[q * 4 + 3], acc0);
            acc1 = fmaf(xq1.w, wreg[q * 4 + 7], acc1);
        }
        float outv = rstd * ((acc0 + acc1) - mean * Sc) + Tc;
        if (lane < 60)
            rt[(size_t)row * RT + outc] = outv;
    }
}

// ---------------------------------------------------------------------------
// Pooled projection (layers 2/3), register-blocked 4 rows x 15 cols; W tile
// in LDS. Writes fused rt[row][64]: r = val*(h@Wrel) cols 0-29;
// t = val*(h@Wroot)+brel cols 32-61.
// ---------------------------------------------------------------------------
__global__ __launch_bounds__(256) void k_proj30p(
    const float* __restrict__ hbuf, const int* __restrict__ sidx,
    const float* __restrict__ score, const float* __restrict__ Wc,
    const float* __restrict__ brel, float* __restrict__ rt,
    int n_old, int k)
{
    __shared__ float wlds[4][32][16];
    for (int i = threadIdx.x; i < 30 * 64; i += 256) {
        int m = i >> 6, cc = i & 63;
        int cg = cc >> 4, j = cc & 15;
        wlds[cg][m][j] = (j < 15) ? Wc[m * 60 + cg * 15 + j] : 0.f;
    }
    __syncthreads();
    int lane = threadIdx.x & 63, cg = threadIdx.x >> 6;
    int row0 = blockIdx.x * 256 + lane;
    float acc[4][15];
#pragma unroll
    for (int ri = 0; ri < 4; ++ri)
#pragma unroll
        for (int c = 0; c < 15; ++c) acc[ri][c] = 0.f;
    float vals[4];
    const float* hp[4];
#pragma unroll
    for (int ri = 0; ri < 4; ++ri) {
        int row = row0 + ri * 64;
        int g = row / k, j = row - g * k;
        int idx = sidx[g * k + j];
        vals[ri] = score[g * n_old + idx];
        hp[ri] = hbuf + (size_t)(g * n_old + idx) * RSTRIDE;
    }
    for (int mb = 0; mb < 7; ++mb) {
        float4 cur[4];
#pragma unroll
        for (int ri = 0; ri < 4; ++ri) cur[ri] = *(const float4*)(hp[ri] + mb * 4);
#pragma unroll
        for (int kk = 0; kk < 4; ++kk) {
            int m = mb * 4 + kk;
            float4 w0 = *(const float4*)&wlds[cg][m][0];
            float4 w1 = *(const float4*)&wlds[cg][m][4];
            float4 w2 = *(const float4*)&wlds[cg][m][8];
            float4 w3 = *(const float4*)&wlds[cg][m][12];
#pragma unroll
            for (int ri = 0; ri < 4; ++ri) {
                float xv = (kk == 0) ? cur[ri].x : (kk == 1) ? cur[ri].y
                          : (kk == 2) ? cur[ri].z : cur[ri].w;
                acc[ri][0]  += xv * w0.x; acc[ri][1]  += xv * w0.y;
                acc[ri][2]  += xv * w0.z; acc[ri][3]  += xv * w0.w;
                acc[ri][4]  += xv * w1.x; acc[ri][5]  += xv * w1.y;
                acc[ri][6]  += xv * w1.z; acc[ri][7]  += xv * w1.w;
                acc[ri][8]  += xv * w2.x; acc[ri][9]  += xv * w2.y;
                acc[ri][10] += xv * w2.z; acc[ri][11] += xv * w2.w;
                acc[ri][12] += xv * w3.x; acc[ri][13] += xv * w3.y;
                acc[ri][14] += xv * w3.z;
            }
        }
    }
    {   // tail m = 28, 29
        float2 h2[4];
#pragma unroll
        for (int ri = 0; ri < 4; ++ri) h2[ri] = *(const float2*)(hp[ri] + 28);
#pragma unroll
        for (int kk = 0; kk < 2; ++kk) {
            int m = 28 + kk;
            float4 w0 = *(const float4*)&wlds[cg][m][0];
            float4 w1 = *(const float4*)&wlds[cg][m][4];
            float4 w2 = *(const float4*)&wlds[cg][m][8];
            float4 w3 = *(const float4*)&wlds[cg][m][12];
#pragma unroll
            for (int ri = 0; ri < 4; ++ri) {
                float xv = (kk == 0) ? h2[ri].x : h2[ri].y;
                acc[ri][0]  += xv * w0.x; acc[ri][1]  += xv * w0.y;
                acc[ri][2]  += xv * w0.z; acc[ri][3]  += xv * w0.w;
                acc[ri][4]  += xv * w1.x; acc[ri][5]  += xv * w1.y;
                acc[ri][6]  += xv * w1.z; acc[ri][7]  += xv * w1.w;
                acc[ri][8]  += xv * w2.x; acc[ri][9]  += xv * w2.y;
                acc[ri][10] += xv * w2.z; acc[ri][11] += xv * w2.w;
                acc[ri][12] += xv * w3.x; acc[ri][13] += xv * w3.y;
                acc[ri][14] += xv * w3.z;
            }
        }
    }
    bool isR = (cg < 2);
    int coff = (isR ? 0 : 32) + (cg & 1) * 15;
    float sB[15];
#pragma unroll
    for (int c = 0; c < 15; ++c) sB[c] = isR ? 0.f : brel[(cg & 1) * 15 + c];
#pragma unroll
    for (int ri = 0; ri < 4; ++ri) {
        int row = row0 + ri * 64;
        float val = vals[ri];
        float* op = rt + (size_t)row * RT + coff;
#pragma unroll
        for (int c = 0; c < 15; ++c)
            op[c] = val * acc[ri][c] + sB[c];
    }
}

// ---------------------------------------------------------------------------
// Layer-1 counting sort (the only sort in the pipeline).
// ---------------------------------------------------------------------------
__global__ __launch_bounds__(1024) void k_hist1(
    const int* __restrict__ dst, unsigned short* __restrict__ rank,
    int* __restrict__ chunkCnt)
{
    __shared__ unsigned int cnt[2048];
    int chunk = blockIdx.x, g = chunk >> 2;
    for (int i = threadIdx.x; i < 2048; i += 1024) cnt[i] = 0;
    __syncthreads();
    int e0 = chunk * 8192;
#pragma unroll
    for (int u = 0; u < 8; ++u) {
        int e = e0 + u * 1024 + threadIdx.x;
        int d = dst[e] - g * N0;
        rank[e] = (unsigned short)atomicAdd(&cnt[d], 1u);
    }
    __syncthreads();
    for (int i = threadIdx.x; i < 2048; i += 1024) chunkCnt[chunk * 2048 + i] = cnt[i];
}

__global__ __launch_bounds__(1024) void k_scan(
    int* __restrict__ chunkCnt, int* __restrict__ runStart, int* __restrict__ runLen)
{
    __shared__ int bufA[2048], bufB[2048];
    int g = blockIdx.x;
    int c0[2], c1[2], c2[2], tt[2];
    for (int h2 = 0; h2 < 2; ++h2) {
        int d = threadIdx.x + h2 * 1024;
        c0[h2] = chunkCnt[(g * 4 + 0) * 2048 + d];
        c1[h2] = chunkCnt[(g * 4 + 1) * 2048 + d];
        c2[h2] = chunkCnt[(g * 4 + 2) * 2048 + d];
        int c3 = chunkCnt[(g * 4 + 3) * 2048 + d];
        tt[h2] = c0[h2] + c1[h2] + c2[h2] + c3;
        bufA[d] = tt[h2];
    }
    __syncthreads();
    int* s_ = bufA; int* d_ = bufB;
    for (int off = 1; off < 2048; off <<= 1) {
        for (int h2 = 0; h2 < 2; ++h2) {
            int d = threadIdx.x + h2 * 1024;
            int v = s_[d];
            if (d >= off) v += s_[d - off];
            d_[d] = v;
        }
        __syncthreads();
        int* tmp = s_; s_ = d_; d_ = tmp;
    }
    for (int h2 = 0; h2 < 2; ++h2) {
        int d = threadIdx.x + h2 * 1024;
        int ex = s_[d] - tt[h2];
        runStart[g * 2048 + d] = ex;
        runLen[g * 2048 + d] = tt[h2];
        chunkCnt[(g * 4 + 0) * 2048 + d] = ex;
        chunkCnt[(g * 4 + 1) * 2048 + d] = ex + c0[h2];
        chunkCnt[(g * 4 + 2) * 2048 + d] = ex + c0[h2] + c1[h2];
        chunkCnt[(g * 4 + 3) * 2048 + d] = ex + c0[h2] + c1[h2] + c2[h2];
    }
}

__global__ __launch_bounds__(1024) void k_scat1(
    const int* __restrict__ src, const int* __restrict__ dst, const float* __restrict__ ew,
    const unsigned short* __restrict__ rank, const int* __restrict__ chunkOff,
    float2* __restrict__ sOut)
{
    int chunk = blockIdx.x, g = chunk >> 2;
    int e0 = chunk * 8192;
#pragma unroll
    for (int u = 0; u < 8; ++u) {
        int e = e0 + u * 1024 + threadIdx.x;
        int d = dst[e] - g * N0;
        int pos = chunkOff[chunk * 2048 + d] + (int)rank[e];
        sOut[(size_t)g * ESTRIDE1 + pos] = make_float2(__int_as_float(src[e]), ew[e]);
    }
}

// ---------------------------------------------------------------------------
// Run-major aggregation over the LAYER-1 CSR for ALL layers. LVL = pooling
// depth: node -> ancestor v1 via sidx chain; per-edge liveness/renumbering
// via mapc (w -> 0 for dropped srcs). Zero atomics; fused +t/relu and score.
// rt layout: r = rt[row][0:30], t = rt[row][32:62], stride 64.
// ---------------------------------------------------------------------------
template<int LVL>
__global__ __launch_bounds__(256) void k_gather(
    const float2* __restrict__ sE, const int* __restrict__ runS, const int* __restrict__ runL,
    const int* __restrict__ ind1, const int* __restrict__ ind2, const int* __restrict__ mapc,
    const float* __restrict__ rt, float* __restrict__ h,
    const float* __restrict__ poolw, float* __restrict__ score,
    int n, int rK, int nblocks)
{
    int b = blockIdx.x;
    int cpx = nblocks >> 3;                 // XCD-chunked swizzle
    b = (b & 7) * cpx + (b >> 3);
    int slot = threadIdx.x >> 5, j = threadIdx.x & 31;
    int v = b * 8 + slot;
    int g = v / n;
    int local = v - g * n;
    int v1 = local;
    if (LVL >= 2) v1 = ind2[g * K2 + v1];
    if (LVL >= 1) v1 = ind1[g * K1 + v1];
    int s0 = runS[g * 2048 + v1], len = runL[g * 2048 + v1];
    const float2* meta = sE + (size_t)g * ESTRIDE1 + s0;
    int rbase = g * rK;
    float acc = 0.f;
    for (int c = 0; c < len; c += 8) {
        int lim = len - c; if (lim > 8) lim = 8;
        float2 m[8];
#pragma unroll
        for (int u = 0; u < 8; ++u) m[u] = meta[c + (u < lim ? u : 0)];
        int rowv[8]; float wv[8];
#pragma unroll
        for (int u = 0; u < 8; ++u) {
            int srcg = __float_as_int(m[u].x);
            float w = (u < lim) ? m[u].y : 0.f;
            if (LVL == 0) {
                rowv[u] = srcg;
            } else {
                int ss = mapc[srcg];
                rowv[u] = rbase + (ss < 0 ? 0 : ss);
                w = (ss < 0) ? 0.f : w;
            }
            wv[u] = w;
        }
#pragma unroll
        for (int u = 0; u < 8; ++u)
            acc += rt[(size_t)rowv[u] * RT + j] * wv[u];
    }
    float wj = (j < H) ? poolw[j] : 0.f;
    float hval = 0.f;
    if (j < H) {
        hval = fmaxf(acc + rt[(size_t)v * RT + 32 + j], 0.f);
        h[(size_t)v * RSTRIDE + j] = hval;
    }
    float p = hval * wj, q = wj * wj;
#pragma unroll
    for (int off = 16; off > 0; off >>= 1) {
        p += __shfl_xor(p, off, 32);
        q += __shfl_xor(q, off, 32);
    }
    if (j == 0) score[v] = tanhf(p / sqrtf(q));
}

// ---------------------------------------------------------------------------
// Top-k (desc score, asc idx; jax.lax.top_k tie-break) + cumulative map.
// ---------------------------------------------------------------------------
__global__ __launch_bounds__(1024) void k_topk_map(
    const float* __restrict__ score, int* __restrict__ sidx, int* __restrict__ mapc,
    int n, int k, int first)
{
    __shared__ unsigned long long keys[2048];
    __shared__ int inv[2048];
    int g = blockIdx.x;
    for (int i = threadIdx.x; i < 2048; i += 1024) {
        unsigned long long key = ~0ull;
        if (i < n) {
            float s = score[g * n + i];
            if (s == 0.f) s = 0.f;                 // canonicalize -0 -> +0
            unsigned u = __float_as_uint(s);
            unsigned asc = (u & 0x80000000u) ? ~u : (u | 0x80000000u);
            unsigned desc = ~asc;
            key = ((unsigned long long)desc << 32) | (unsigned)i;
        }
        keys[i] = key;
        inv[i] = -1;
    }
    __syncthreads();
    for (int kk = 2; kk <= 2048; kk <<= 1) {
        for (int jj = kk >> 1; jj > 0; jj >>= 1) {
            for (int i = threadIdx.x; i < 2048; i += 1024) {
                int ixj = i ^ jj;
                if (ixj > i) {
                    unsigned long long a = keys[i], bb = keys[ixj];
                    bool up = ((i & kk) == 0);
                    if ((a > bb) == up) { keys[i] = bb; keys[ixj] = a; }
                }
            }
            __syncthreads();
        }
    }
    for (int j = threadIdx.x; j < k; j += 1024) {
        int idx = (int)(keys[j] & 0xffffffffu);
        sidx[g * k + j] = idx;
        inv[idx] = j;
    }
    __syncthreads();
    if (first) {
        for (int v = threadIdx.x; v < N0; v += 1024)
            mapc[g * N0 + v] = inv[v];
    } else {
        for (int v = threadIdx.x; v < N0; v += 1024) {
            int m = mapc[g * N0 + v];
            mapc[g * N0 + v] = (m >= 0) ? inv[m] : -1;
        }
    }
}

// ---------------------------------------------------------------------------
// Segmented readout: grid (RSEG, B). Partial [max;sum] over a row slice.
// ---------------------------------------------------------------------------
__global__ __launch_bounds__(256) void k_rpart(
    const float* __restrict__ hbuf, const int* __restrict__ sidx,
    const float* __restrict__ score, float* __restrict__ pmax, float* __restrict__ psum,
    int n_old, int k)
{
    __shared__ float smax[8][32], ssum[8][32];
    int g = blockIdx.y, seg = blockIdx.x;
    int clen = (k + RSEG - 1) / RSEG;
    int start = seg * clen;
    int end = start + clen; if (end > k) end = k;
    int f = threadIdx.x & 31, rr = threadIdx.x >> 5;
    float mx = -INFINITY, sm = 0.f;
    if (f < H) {
        for (int j = start + rr; j < end; j += 8) {
            int idx = sidx[g * k + j];
            float val = score[g * n_old + idx];
            float v = hbuf[(size_t)(g * n_old + idx) * RSTRIDE + f] * val;
            mx = fmaxf(mx, v);
            sm += v;
        }
    }
    smax[rr][f] = mx; ssum[rr][f] = sm;
    __syncthreads();
    if (rr == 0) {
        for (int q = 1; q < 8; ++q) { mx = fmaxf(mx, smax[q][f]); sm += ssum[q][f]; }
        pmax[(g * RSEG + seg) * 32 + f] = mx;
        psum[(g * RSEG + seg) * 32 + f] = sm;
    }
}

// Finalize all 3 readouts + z = relu(x1+x2+x3). grid B, block 64.
__global__ __launch_bounds__(64) void k_zfin(
    const float* __restrict__ pm1, const float* __restrict__ ps1,
    const float* __restrict__ pm2, const float* __restrict__ ps2,
    const float* __restrict__ pm3, const float* __restrict__ ps3,
    float* __restrict__ z)
{
    int g = blockIdx.x, c = threadIdx.x;
    if (c >= 60) return;
    float v1, v2, v3;
    if (c < H) {
        float m1 = -INFINITY, m2 = -INFINITY, m3 = -INFINITY;
        for (int s = 0; s < RSEG; ++s) {
            m1 = fmaxf(m1, pm1[(g * RSEG + s) * 32 + c]);
            m2 = fmaxf(m2, pm2[(g * RSEG + s) * 32 + c]);
            m3 = fmaxf(m3, pm3[(g * RSEG + s) * 32 + c]);
        }
        v1 = m1; v2 = m2; v3 = m3;
    } else {
        int f = c - H;
        float s1 = 0.f, s2 = 0.f, s3 = 0.f;
        for (int s = 0; s < RSEG; ++s) {
            s1 += ps1[(g * RSEG + s) * 32 + f];
            s2 += ps2[(g * RSEG + s) * 32 + f];
            s3 += ps3[(g * RSEG + s) * 32 + f];
        }
        v1 = s1 / (float)K1; v2 = s2 / (float)K2; v3 = s3 / (float)K3;
    }
    z[g * 60 + c] = fmaxf(v1 + v2 + v3, 0.f);
}

// a1[h,b,o] = relu(sum_d z[b,d]*W1[h,d,o] + b1[h,o]),  o<240, d<60
__global__ __launch_bounds__(256) void k_mlp1(
    const float* __restrict__ z, const float* __restrict__ W,
    const float* __restrict__ bias, float* __restrict__ a)
{
    int hb = blockIdx.x, hh = hb >> 6, b = hb & 63;
    __shared__ float zr[60];
    if (threadIdx.x < 60) zr[threadIdx.x] = z[b * 60 + threadIdx.x];
    __syncthreads();
    int o = threadIdx.x;
    if (o < 240) {
        float acc = bias[hh * 240 + o];
        const float* Wp = W + hh * 60 * 240;
#pragma unroll
        for (int d = 0; d < 60; ++d) acc += zr[d] * Wp[d * 240 + o];
        a[(hh * B + b) * 240 + o] = fmaxf(acc, 0.f);
    }
}

// a2 GEMM: grid (11 heads x 15 col-tiles of 64); a1 tile in LDS.
__global__ __launch_bounds__(256) void k_mlp2(
    const float* __restrict__ a1, const float* __restrict__ W,
    const float* __restrict__ bias, float* __restrict__ a2)
{
    __shared__ float a1t[64 * 240];
    int hh = blockIdx.x / 15, ct = blockIdx.x % 15;
    const float4* ag = (const float4*)(a1 + (size_t)hh * B * 240);
    for (int i = threadIdx.x; i < 64 * 240 / 4; i += 256)
        ((float4*)a1t)[i] = ag[i];
    __syncthreads();
    int col = threadIdx.x & 63, rg = threadIdx.x >> 6;
    const float* Wp = W + (size_t)hh * 240 * 960 + ct * 64 + col;
    float acc[16];
#pragma unroll
    for (int i = 0; i < 16; ++i) acc[i] = 0.f;
#pragma unroll 4
    for (int o = 0; o < 240; ++o) {
        float w = Wp[(size_t)o * 960];
        const float* ar = &a1t[0];
#pragma unroll
        for (int i = 0; i < 16; ++i)
            acc[i] += w * ar[(rg * 16 + i) * 240 + o];
    }
    float bv = bias[hh * 960 + ct * 64 + col];
#pragma unroll
    for (int i = 0; i < 16; ++i)
        a2[((size_t)hh * B + rg * 16 + i) * 960 + ct * 64 + col] =
            fmaxf(acc[i] + bv, 0.f);
}

// out[h,b,q] = sum_p a2[h,b,p]*W3[h,p,q] + b3[h,q],  q<8, p<960
__global__ __launch_bounds__(64) void k_mlp3(
    const float* __restrict__ a2, const float* __restrict__ W,
    const float* __restrict__ bias, float* __restrict__ out)
{
    int hb = blockIdx.x, hh = hb >> 6, b = hb & 63;
    __shared__ float ar[960];
    __shared__ float part[64];
    for (int i = threadIdx.x; i < 960; i += 64) ar[i] = a2[(hh * B + b) * 960 + i];
    __syncthreads();
    int q = threadIdx.x & 7, c = threadIdx.x >> 3;
    const float* Wp = W + hh * 960 * 8;
    float acc = 0.f;
    for (int p = c; p < 960; p += 8) acc += ar[p] * Wp[p * 8 + q];
    part[threadIdx.x] = acc;
    __syncthreads();
    if (threadIdx.x < 8) {
        float s = bias[hh * 8 + threadIdx.x];
        for (int cc = 0; cc < 8; ++cc) s += part[cc * 8 + threadIdx.x];
        out[(hh * B + b) * 8 + threadIdx.x] = s;
    }
}

// ---------------------------------------------------------------------------
extern "C" void kernel_launch(void* const* d_in, const int* in_sizes, int n_in,
                              void* d_out, int out_size, void* d_ws, size_t ws_size,
                              hipStream_t stream)
{
    const float* x       = (const float*)d_in[0];
    const int*   eidx    = (const int*)d_in[1];
    const int*   src0    = eidx;
    const int*   dst0    = eidx + ETOT;
    const float* ew0     = (const float*)d_in[2];
    const float* ln_g    = (const float*)d_in[4];
    const float* ln_b    = (const float*)d_in[5];
    const float* W_rel1  = (const float*)d_in[6];
    const float* b_rel1  = (const float*)d_in[7];
    const float* W_root1 = (const float*)d_in[8];
    const float* W_rel2  = (const float*)d_in[9];
    const float* b_rel2  = (const float*)d_in[10];
    const float* W_root2 = (const float*)d_in[11];
    const float* W_rel3  = (const float*)d_in[12];
    const float* b_rel3  = (const float*)d_in[13];
    const float* W_root3 = (const float*)d_in[14];
    const float* pool_w1 = (const float*)d_in[15];
    const float* pool_w2 = (const float*)d_in[16];
    const float* pool_w3 = (const float*)d_in[17];
    const float* head_W1 = (const float*)d_in[18];
    const float* head_b1 = (const float*)d_in[19];
    const float* head_W2 = (const float*)d_in[20];
    const float* head_b2 = (const float*)d_in[21];
    const float* head_W3 = (const float*)d_in[22];
    const float* head_b3 = (const float*)d_in[23];

    // ---- workspace carve (~72 MB) ----
    float* ws     = (float*)d_ws;
    float* rtbuf  = ws;                               // NTOT*64 (fused r|t)
    float* abuf   = rtbuf + (size_t)NTOT * RT;        // NTOT*32 (h)
    float2* sA    = (float2*)(abuf + (size_t)NTOT * RSTRIDE); // B*ESTRIDE1
    float* score  = (float*)(sA + (size_t)B * ESTRIDE1);      // NTOT
    int*   sidxA  = (int*)(score + NTOT);             // B*K1
    int*   sidxB  = sidxA + B * K1;                   // B*K2
    int*   sidxC  = sidxB + B * K2;                   // B*K3
    int*   mapc   = sidxC + B * K3;                   // NTOT
    int*   runSA  = mapc + NTOT;                      // B*2048
    int*   runLA  = runSA + B * 2048;                 // B*2048
    float* pm1    = (float*)(runLA + B * 2048);       // B*RSEG*32 each
    float* ps1    = pm1 + B * RSEG * 32;
    float* pm2    = ps1 + B * RSEG * 32;
    float* ps2    = pm2 + B * RSEG * 32;
    float* pm3    = ps2 + B * RSEG * 32;
    float* ps3    = pm3 + B * RSEG * 32;
    float* zb     = ps3 + B * RSEG * 32;              // B*60
    float* Wc1    = zb + B * 60;                      // 128*60
    float* S1     = Wc1 + IN_DIM * 60;
    float* T1     = S1 + 60;
    float* Wc2    = T1 + 60;                          // 30*60
    float* Wc3    = Wc2 + H * 60;
    // aliases into abuf (dead before gather<0>): chunk counters + edge ranks
    int* chunkBuf         = (int*)abuf;                                  // 256*2048 ints
    unsigned short* rank  = (unsigned short*)((char*)abuf + (4u << 20)); // ETOT u16
    // heads alias rtbuf (dead after layer-3 gather)
    float* a1 = rtbuf;
    float* a2 = a1 + NH * B * 240;

    k_prep<<<1, 256, 0, stream>>>(ln_g, ln_b, W_rel1, b_rel1, W_root1,
                                  W_rel2, W_root2, W_rel3, W_root3,
                                  Wc1, S1, T1, Wc2, Wc3);

    // ---- layer-1 CSR (the only sort) ----
    k_hist1<<<256, 1024, 0, stream>>>(dst0, rank, chunkBuf);
    k_scan<<<B, 1024, 0, stream>>>(chunkBuf, runSA, runLA);
    k_scat1<<<256, 1024, 0, stream>>>(src0, dst0, ew0, rank, chunkBuf, sA);

    // ---- layer 1 ----
    k_lnproj<<<NTOT / 256, 256, 0, stream>>>(x, Wc1, S1, T1, rtbuf);
    k_gather<0><<<NTOT / 8, 256, 0, stream>>>(sA, runSA, runLA, nullptr, nullptr, nullptr,
                                              rtbuf, abuf, pool_w1, score,
                                              N0, N0, NTOT / 8);
    k_topk_map<<<B, 1024, 0, stream>>>(score, sidxA, mapc, N0, K1, 1);
    k_rpart<<<dim3(RSEG, B), 256, 0, stream>>>(abuf, sidxA, score, pm1, ps1, N0, K1);
    k_proj30p<<<B * K1 / 256, 256, 0, stream>>>(abuf, sidxA, score, Wc2, b_rel2,
                                                rtbuf, N0, K1);

    // ---- layer 2 (no sort: reuse layer-1 runs via sidxA + mapc filter) ----
    k_gather<1><<<B * K1 / 8, 256, 0, stream>>>(sA, runSA, runLA, sidxA, nullptr, mapc,
                                                rtbuf, abuf, pool_w2, score,
                                                K1, K1, B * K1 / 8);
    k_topk_map<<<B, 1024, 0, stream>>>(score, sidxB, mapc, K1, K2, 0);
    k_rpart<<<dim3(RSEG, B), 256, 0, stream>>>(abuf, sidxB, score, pm2, ps2, K1, K2);
    k_proj30p<<<B * K2 / 256, 256, 0, stream>>>(abuf, sidxB, score, Wc3, b_rel3,
                                                rtbuf, K1, K2);

    // ---- layer 3 ----
    k_gather<2><<<B * K2 / 8, 256, 0, stream>>>(sA, runSA, runLA, sidxA, sidxB, mapc,
                                                rtbuf, abuf, pool_w3, score,
                                                K2, K2, B * K2 / 8);
    k_topk_map<<<B, 1024, 0, stream>>>(score, sidxC, mapc, K2, K3, 0);
    k_rpart<<<dim3(RSEG, B), 256, 0, stream>>>(abuf, sidxC, score, pm3, ps3, K2, K3);

    // ---- heads ----
    k_zfin<<<B, 64, 0, stream>>>(pm1, ps1, pm2, ps2, pm3, ps3, zb);
    k_mlp1<<<NH * B, 256, 0, stream>>>(zb, head_W1, head_b1, a1);
    k_mlp2<<<NH * 15, 256, 0, stream>>>(a1, head_W2, head_b2, a2);
    k_mlp3<<<NH * B, 64, 0, stream>>>(a2, head_W3, head_b3, (float*)d_out);
}